// Round 1
// 529.899 us; speedup vs baseline: 1.1171x; 1.1171x over previous
//
#include <hip/hip_runtime.h>
#include <hip/hip_bf16.h>
#include <math.h>

typedef __attribute__((ext_vector_type(8))) __bf16 bf16x8;
typedef __attribute__((ext_vector_type(4))) float f32x4;

#define BM 256
#define BN 256
#define BK 64

__device__ __forceinline__ void glds16(const void* g, void* l) {
  __builtin_amdgcn_global_load_lds(
      (const __attribute__((address_space(1))) void*)g,
      (__attribute__((address_space(3))) void*)l, 16, 0, 0);
}

__device__ __forceinline__ unsigned short f2bf(float f) {
  __hip_bfloat16 h = __float2bfloat16(f);
  return __builtin_bit_cast(unsigned short, h);
}

// ---------------- Fused prep: per-token quant (blocks [0,T)) ----------------
// ----------------        + groupwise weight dequant (blocks [T,T+O)) -------
__global__ void prep_fused(const float* __restrict__ x,
                           ushort* __restrict__ xq, int T,
                           const int* __restrict__ w,
                           const float* __restrict__ scales,
                           const float* __restrict__ zeros,
                           ushort* __restrict__ wq, int I, int G) {
  const int tid = threadIdx.x;
  if (blockIdx.x < (unsigned)T) {
    // ---- per-token int8 fake-quant -> bf16 (one block per token row) ----
    const int row = blockIdx.x;
    const float4* xr = (const float4*)(x + (size_t)row * I);
    float4 v[4];
    float mn = 0.f, mx = 0.f;  // reference clamps min<=0, max>=0
#pragma unroll
    for (int i = 0; i < 4; ++i) {
      v[i] = xr[tid + i * 256];
      mn = fminf(mn, fminf(fminf(v[i].x, v[i].y), fminf(v[i].z, v[i].w)));
      mx = fmaxf(mx, fmaxf(fmaxf(v[i].x, v[i].y), fmaxf(v[i].z, v[i].w)));
    }
#pragma unroll
    for (int off = 32; off > 0; off >>= 1) {
      mn = fminf(mn, __shfl_down(mn, off));
      mx = fmaxf(mx, __shfl_down(mx, off));
    }
    __shared__ float smn[4], smx[4], sp[3];
    const int wave = tid >> 6, lane = tid & 63;
    if (lane == 0) { smn[wave] = mn; smx[wave] = mx; }
    __syncthreads();
    if (tid == 0) {
      mn = fminf(fminf(smn[0], smn[1]), fminf(smn[2], smn[3]));
      mx = fmaxf(fmaxf(smx[0], smx[1]), fmaxf(smx[2], smx[3]));
      float scale = fmaxf((mx - mn) / 255.0f, 1.1920928955078125e-07f);
      float dmin = mn / scale, dmax = mx / scale;
      float zp = ((-128.0f + dmin) + (127.0f + dmax) > 0.0f)
                     ? (-128.0f - dmin)
                     : (127.0f - dmax);
      zp = rintf(fminf(fmaxf(zp, -128.0f), 127.0f));  // jnp.round = RNE
      sp[0] = scale;
      sp[1] = zp;
      sp[2] = 1.0f / scale;
    }
    __syncthreads();
    const float scale = sp[0], zp = sp[1], rs = sp[2];
    ushort4* xo = (ushort4*)(xq + (size_t)row * I);
#pragma unroll
    for (int i = 0; i < 4; ++i) {
      ushort4 o;
      float q;
      q = fminf(fmaxf(rintf(v[i].x * rs) + zp, -128.f), 127.f);
      o.x = f2bf((q - zp) * scale);
      q = fminf(fmaxf(rintf(v[i].y * rs) + zp, -128.f), 127.f);
      o.y = f2bf((q - zp) * scale);
      q = fminf(fmaxf(rintf(v[i].z * rs) + zp, -128.f), 127.f);
      o.z = f2bf((q - zp) * scale);
      q = fminf(fmaxf(rintf(v[i].w * rs) + zp, -128.f), 127.f);
      o.w = f2bf((q - zp) * scale);
      xo[tid + i * 256] = o;
    }
  } else {
    // ---- groupwise int4 weight dequant -> bf16 (one block per out row) ----
    const int o = blockIdx.x - T;
    const int4* wr = (const int4*)(w + (size_t)o * I);
    ushort4* wo = (ushort4*)(wq + (size_t)o * I);
#pragma unroll
    for (int it = 0; it < 4; ++it) {
      const int chunk = it * 256 + tid;  // chunk of 4 elements
      const int g = chunk >> 6;          // (chunk*4)/256
      const float s = scales[(size_t)o * G + g];
      const float z = zeros[(size_t)o * G + g];
      const int4 wv = wr[chunk];
      ushort4 ov;
      ov.x = f2bf(((float)wv.x - z) * s);
      ov.y = f2bf(((float)wv.y - z) * s);
      ov.z = f2bf(((float)wv.z - z) * s);
      ov.w = f2bf(((float)wv.w - z) * s);
      wo[chunk] = ov;
    }
  }
}

// ---------------- bf16 NT GEMM: 256x256 tile, BK=64, 8 waves, 8-phase ------
// C[M,N] = A[M,K] * B[N,K]^T.
// Schedule = the 256^2 8-phase template (T1+T2+T3+T4+T5):
//   - 2 LDS K-tile buffers (A+B, 128 KiB total), chunk-XOR swizzle (zero
//     bank conflicts, proven in the 128^2 predecessor).
//   - per K-tile 4 phases, each {ds_read quadrant | stage 1 half-tile ->
//     raw s_barrier -> setprio(1) 16 MFMA setprio(0) -> s_barrier}.
//   - counted s_waitcnt vmcnt(4) once per K-tile (never 0 in steady state):
//     the 2 B half-tiles of kt+2 just issued stay in flight across the
//     barrier. Staging targets regions whose last reader finished one
//     phase earlier (B of cur free after ph2, A of nxt free since kt-1 ph3).
// Per wave: 128x64 output = acc[8][4] f32x4 (128 VGPR), a[4][2]+b[4][2]
// bf16x8 frags (64 VGPR).
__global__ __launch_bounds__(512, 2) void gemm_bt256(
    const ushort* __restrict__ A, const ushort* __restrict__ B,
    float* __restrict__ C, int M, int N, int K) {
  __shared__ __align__(16) ushort As[2][BM * BK];
  __shared__ __align__(16) ushort Bs[2][BN * BK];
  const int tid = threadIdx.x;
  const int wave = tid >> 6, lane = tid & 63;
  const int wm = wave >> 2;  // 0..1  M half (128 rows)
  const int wn = wave & 3;   // 0..3  N quarter (64 cols)

  // XCD-aware bijective swizzle: consecutive blockIdx round-robin XCDs;
  // remap so each XCD owns a contiguous chunk of tile space (nwg % 8 == 0).
  const int nwg = gridDim.x;
  const int bid = blockIdx.x;
  const int swz =
      ((nwg & 7) == 0) ? ((bid & 7) * (nwg >> 3) + (bid >> 3)) : bid;
  const int ntn = N / BN;
  const int by = swz / ntn, bx = swz % ntn;
  const int bm0 = by * BM, bn0 = bx * BN;

  // --- staging addressing (global_load_lds: wave-uniform LDS base +
  // lane*16B; the global source is pre-swizzled so physical chunk c of
  // row r holds logical k-chunk c ^ (r&7)) ---
  const int ldr = lane >> 3;                // row within 8-row slab
  const int ldc = ((lane & 7) ^ ldr) * 8;   // swizzled k offset (elems)
  const ushort* Ag = A + (size_t)(bm0 + wave * 16 + ldr) * K + ldc;
  const ushort* Bg = B + (size_t)(bn0 + wave * 16 + ldr) * K + ldc;

#define STAGE_A(b, h, kt)                                          \
  do {                                                             \
    glds16(Ag + (size_t)((h) * 128) * K + (size_t)(kt) * BK,       \
           &As[b][((h) * 128 + wave * 16) * BK]);                  \
    glds16(Ag + (size_t)((h) * 128 + 8) * K + (size_t)(kt) * BK,   \
           &As[b][((h) * 128 + wave * 16 + 8) * BK]);              \
  } while (0)
#define STAGE_B(b, h, kt)                                          \
  do {                                                             \
    glds16(Bg + (size_t)((h) * 128) * K + (size_t)(kt) * BK,       \
           &Bs[b][((h) * 128 + wave * 16) * BK]);                  \
    glds16(Bg + (size_t)((h) * 128 + 8) * K + (size_t)(kt) * BK,   \
           &Bs[b][((h) * 128 + wave * 16 + 8) * BK]);              \
  } while (0)

  // --- fragment read addressing (16x16x32 A/B layout: lane holds row
  // lane&15, k-elems [(lane>>4)*8, +8); physical chunk = logical ^ (row&7))
  const int mrow = lane & 15;
  const int kc = lane >> 4;
  const int sw = mrow & 7;
  const int c0 = (kc ^ sw) * 8;        // ks=0 chunk byte-offset/2
  const int c1 = ((4 + kc) ^ sw) * 8;  // ks=1
  const int aBase = (wm * 128 + mrow) * BK;
  const int bBase = (wn * 64 + mrow) * BK;

  f32x4 acc[8][4];
#pragma unroll
  for (int i = 0; i < 8; ++i)
#pragma unroll
    for (int j = 0; j < 4; ++j) acc[i][j] = (f32x4){0.f, 0.f, 0.f, 0.f};

  const int NT = K / BK;  // assumes NT >= 2 (K=4096 -> 64)

  // ---- prologue: kt0 fully + B(kt1); wait for kt0 (4 loads left in air) --
  STAGE_A(0, 0, 0);
  STAGE_A(0, 1, 0);
  STAGE_B(0, 0, 0);
  STAGE_B(0, 1, 0);
  STAGE_B(1, 0, 1);
  STAGE_B(1, 1, 1);
  __builtin_amdgcn_sched_barrier(0);
  asm volatile("s_waitcnt vmcnt(4)" ::: "memory");
  __builtin_amdgcn_s_barrier();

  bf16x8 a[4][2], b[4][2];

  for (int kt = 0; kt < NT; ++kt) {
    const int cur = kt & 1, nxt = cur ^ 1;
    const ushort* Ac = As[cur];
    const ushort* Bc = Bs[cur];

    // ================= phase 1: (m0-3) x (n0-1) =================
#pragma unroll
    for (int mi = 0; mi < 4; ++mi) {
      a[mi][0] = *(const bf16x8*)&Ac[aBase + mi * (16 * BK) + c0];
      a[mi][1] = *(const bf16x8*)&Ac[aBase + mi * (16 * BK) + c1];
    }
#pragma unroll
    for (int ni = 0; ni < 2; ++ni) {
      b[ni][0] = *(const bf16x8*)&Bc[bBase + ni * (16 * BK) + c0];
      b[ni][1] = *(const bf16x8*)&Bc[bBase + ni * (16 * BK) + c1];
    }
    if (kt + 1 < NT) STAGE_A(nxt, 0, kt + 1);  // A region of nxt free since kt-1 ph3
    __builtin_amdgcn_sched_barrier(0);
    __builtin_amdgcn_s_barrier();
    __builtin_amdgcn_s_setprio(1);
#pragma unroll
    for (int ks = 0; ks < 2; ++ks)
#pragma unroll
      for (int mi = 0; mi < 4; ++mi)
#pragma unroll
        for (int ni = 0; ni < 2; ++ni)
          acc[mi][ni] = __builtin_amdgcn_mfma_f32_16x16x32_bf16(
              a[mi][ks], b[ni][ks], acc[mi][ni], 0, 0, 0);
    __builtin_amdgcn_s_setprio(0);
    __builtin_amdgcn_sched_barrier(0);
    __builtin_amdgcn_s_barrier();

    // ================= phase 2: (m0-3) x (n2-3) =================
#pragma unroll
    for (int ni = 2; ni < 4; ++ni) {
      b[ni][0] = *(const bf16x8*)&Bc[bBase + ni * (16 * BK) + c0];
      b[ni][1] = *(const bf16x8*)&Bc[bBase + ni * (16 * BK) + c1];
    }
    if (kt + 1 < NT) STAGE_A(nxt, 1, kt + 1);
    __builtin_amdgcn_sched_barrier(0);
    __builtin_amdgcn_s_barrier();
    __builtin_amdgcn_s_setprio(1);
#pragma unroll
    for (int ks = 0; ks < 2; ++ks)
#pragma unroll
      for (int mi = 0; mi < 4; ++mi)
#pragma unroll
        for (int ni = 2; ni < 4; ++ni)
          acc[mi][ni] = __builtin_amdgcn_mfma_f32_16x16x32_bf16(
              a[mi][ks], b[ni][ks], acc[mi][ni], 0, 0, 0);
    __builtin_amdgcn_s_setprio(0);
    __builtin_amdgcn_sched_barrier(0);
    __builtin_amdgcn_s_barrier();

    // ================= phase 3: (m4-7) x (n2-3) =================
#pragma unroll
    for (int mi = 0; mi < 4; ++mi) {
      a[mi][0] = *(const bf16x8*)&Ac[aBase + (mi + 4) * (16 * BK) + c0];
      a[mi][1] = *(const bf16x8*)&Ac[aBase + (mi + 4) * (16 * BK) + c1];
    }
    if (kt + 2 < NT) STAGE_B(cur, 0, kt + 2);  // B of cur fully read after ph2
    __builtin_amdgcn_sched_barrier(0);
    __builtin_amdgcn_s_barrier();
    __builtin_amdgcn_s_setprio(1);
#pragma unroll
    for (int ks = 0; ks < 2; ++ks)
#pragma unroll
      for (int mi = 0; mi < 4; ++mi)
#pragma unroll
        for (int ni = 2; ni < 4; ++ni)
          acc[mi + 4][ni] = __builtin_amdgcn_mfma_f32_16x16x32_bf16(
              a[mi][ks], b[ni][ks], acc[mi + 4][ni], 0, 0, 0);
    __builtin_amdgcn_s_setprio(0);
    __builtin_amdgcn_sched_barrier(0);
    __builtin_amdgcn_s_barrier();

    // ================= phase 4: (m4-7) x (n0-1) =================
    if (kt + 2 < NT) STAGE_B(cur, 1, kt + 2);
    __builtin_amdgcn_sched_barrier(0);
    // counted drain: force A(kt+1)+B(kt+1) landed; leave B(kt+2) (4 loads)
    // in flight across the barrier. Tail tiles drain fully.
    if (kt < NT - 2)
      asm volatile("s_waitcnt vmcnt(4)" ::: "memory");
    else
      asm volatile("s_waitcnt vmcnt(0)" ::: "memory");
    __builtin_amdgcn_s_barrier();
    __builtin_amdgcn_s_setprio(1);
#pragma unroll
    for (int ks = 0; ks < 2; ++ks)
#pragma unroll
      for (int mi = 0; mi < 4; ++mi)
#pragma unroll
        for (int ni = 0; ni < 2; ++ni)
          acc[mi + 4][ni] = __builtin_amdgcn_mfma_f32_16x16x32_bf16(
              a[mi][ks], b[ni][ks], acc[mi + 4][ni], 0, 0, 0);
    __builtin_amdgcn_s_setprio(0);
    __builtin_amdgcn_sched_barrier(0);
    __builtin_amdgcn_s_barrier();
  }

  // epilogue: C/D layout col=lane&15, row=(lane>>4)*4+reg
  const int col = lane & 15;
  const int rq = (lane >> 4) * 4;
#pragma unroll
  for (int mi = 0; mi < 8; ++mi)
#pragma unroll
    for (int ni = 0; ni < 4; ++ni) {
      const int r0 = bm0 + wm * 128 + mi * 16 + rq;
      const int c = bn0 + wn * 64 + ni * 16 + col;
#pragma unroll
      for (int r = 0; r < 4; ++r)
        C[(size_t)(r0 + r) * N + c] = acc[mi][ni][r];
    }
#undef STAGE_A
#undef STAGE_B
}

extern "C" void kernel_launch(void* const* d_in, const int* in_sizes, int n_in,
                              void* d_out, int out_size, void* d_ws,
                              size_t ws_size, hipStream_t stream) {
  const float* x = (const float*)d_in[0];
  const int* w = (const int*)d_in[1];
  const float* scales = (const float*)d_in[2];
  const float* zeros = (const float*)d_in[3];
  float* out = (float*)d_out;

  // derive shapes: in_sizes[0]=T*I, in_sizes[1]=O*I, out_size=T*O
  const double ii =
      sqrt((double)in_sizes[0] * (double)in_sizes[1] / (double)out_size);
  const int I = (int)(ii + 0.5);
  const int T = in_sizes[0] / I;
  const int O = in_sizes[1] / I;
  const int G = I / 256;

  ushort* xq = (ushort*)d_ws;       // T*I bf16
  ushort* wq = xq + (size_t)T * I;  // O*I bf16

  prep_fused<<<T + O, 256, 0, stream>>>(x, xq, T, w, scales, zeros, wq, I, G);
  gemm_bt256<<<(O / BN) * (T / BM), 512, 0, stream>>>(xq, wq, out, T, O, I);
}

// Round 2
// 517.844 us; speedup vs baseline: 1.1431x; 1.0233x over previous
//
#include <hip/hip_runtime.h>
#include <hip/hip_bf16.h>
#include <math.h>

typedef __attribute__((ext_vector_type(8))) __bf16 bf16x8;
typedef __attribute__((ext_vector_type(4))) float f32x4;

#define BM 256
#define BN 256
#define BK 64

__device__ __forceinline__ void glds16(const void* g, void* l) {
  __builtin_amdgcn_global_load_lds(
      (const __attribute__((address_space(1))) void*)g,
      (__attribute__((address_space(3))) void*)l, 16, 0, 0);
}

__device__ __forceinline__ unsigned short f2bf(float f) {
  __hip_bfloat16 h = __float2bfloat16(f);
  return __builtin_bit_cast(unsigned short, h);
}

// ---------------- Fused prep, streaming rewrite ----------------------------
// x-path  (blocks [0, T/4)):  one token row PER WAVE. Lane holds the whole
//   row slice in registers (16 x float4 = 64 floats, all loads in flight),
//   butterfly shfl_xor allreduce for min/max (no LDS, no barriers), every
//   lane computes qparams redundantly (kills the thread-0 serial section),
//   quantizes from registers. 4 rows per 256-thread block.
// w-path  (blocks [T/4, T/4 + O*I/8192)): flat streaming. Each block owns a
//   contiguous span of 2048 int4-chunks; 8 independent fully-unrolled
//   16B loads per thread. A wave's 64 consecutive chunks = exactly one
//   256-elem quant group -> group index is wave-uniform; readfirstlane
//   forces scales/zeros into scalar loads.
__global__ __launch_bounds__(256) void prep_fused(
    const float* __restrict__ x, ushort* __restrict__ xq, int T,
    const int* __restrict__ w, const float* __restrict__ scales,
    const float* __restrict__ zeros, ushort* __restrict__ wq, int I, int G) {
  const int tid = threadIdx.x;
  const int wave = tid >> 6, lane = tid & 63;
  const int XB = T >> 2;  // 4 rows (one per wave) per block
  if (blockIdx.x < (unsigned)XB) {
    const int row = blockIdx.x * 4 + wave;
    const float4* xr = (const float4*)(x + (size_t)row * I);
    float4 v[16];  // I/4 float4 per row / 64 lanes = 16 (I = 4096)
#pragma unroll
    for (int j = 0; j < 16; ++j) v[j] = xr[lane + j * 64];
    float mn = 0.f, mx = 0.f;  // reference clamps min<=0, max>=0
#pragma unroll
    for (int j = 0; j < 16; ++j) {
      mn = fminf(mn, fminf(fminf(v[j].x, v[j].y), fminf(v[j].z, v[j].w)));
      mx = fmaxf(mx, fmaxf(fmaxf(v[j].x, v[j].y), fmaxf(v[j].z, v[j].w)));
    }
#pragma unroll
    for (int off = 32; off > 0; off >>= 1) {
      mn = fminf(mn, __shfl_xor(mn, off));
      mx = fmaxf(mx, __shfl_xor(mx, off));
    }
    // all lanes compute qparams (redundant, but no serialization/barrier)
    const float scale =
        fmaxf((mx - mn) / 255.0f, 1.1920928955078125e-07f);
    const float dmin = mn / scale, dmax = mx / scale;
    float zp = ((-128.0f + dmin) + (127.0f + dmax) > 0.0f)
                   ? (-128.0f - dmin)
                   : (127.0f - dmax);
    zp = rintf(fminf(fmaxf(zp, -128.0f), 127.0f));  // jnp.round = RNE
    const float rs = 1.0f / scale;
    ushort4* xo = (ushort4*)(xq + (size_t)row * I);
#pragma unroll
    for (int j = 0; j < 16; ++j) {
      ushort4 o;
      float q;
      q = fminf(fmaxf(rintf(v[j].x * rs) + zp, -128.f), 127.f);
      o.x = f2bf((q - zp) * scale);
      q = fminf(fmaxf(rintf(v[j].y * rs) + zp, -128.f), 127.f);
      o.y = f2bf((q - zp) * scale);
      q = fminf(fmaxf(rintf(v[j].z * rs) + zp, -128.f), 127.f);
      o.z = f2bf((q - zp) * scale);
      q = fminf(fmaxf(rintf(v[j].w * rs) + zp, -128.f), 127.f);
      o.w = f2bf((q - zp) * scale);
      xo[lane + j * 64] = o;
    }
  } else {
    // ---- groupwise int4 weight dequant -> bf16, flat streaming ----
    const long long base = (long long)(blockIdx.x - XB) * 2048 + tid;
    const int4* wr = (const int4*)w;
    ushort4* wo = (ushort4*)wq;
    int4 wv[8];
#pragma unroll
    for (int it = 0; it < 8; ++it) wv[it] = wr[base + (size_t)it * 256];
#pragma unroll
    for (int it = 0; it < 8; ++it) {
      const long long c = base + (size_t)it * 256;
      // global 256-elem group id = (c*4)/256 = c>>6; wave-uniform.
      const int g = __builtin_amdgcn_readfirstlane((int)(c >> 6));
      const float s = scales[g];
      const float z = zeros[g];
      ushort4 ov;
      ov.x = f2bf(((float)wv[it].x - z) * s);
      ov.y = f2bf(((float)wv[it].y - z) * s);
      ov.z = f2bf(((float)wv[it].z - z) * s);
      ov.w = f2bf(((float)wv[it].w - z) * s);
      wo[c] = ov;
    }
  }
}

// ---------------- bf16 NT GEMM: 256x256 tile, BK=64, 8 waves, 8-phase ------
// (byte-identical to R1 — kept fixed this round for clean attribution)
__global__ __launch_bounds__(512, 2) void gemm_bt256(
    const ushort* __restrict__ A, const ushort* __restrict__ B,
    float* __restrict__ C, int M, int N, int K) {
  __shared__ __align__(16) ushort As[2][BM * BK];
  __shared__ __align__(16) ushort Bs[2][BN * BK];
  const int tid = threadIdx.x;
  const int wave = tid >> 6, lane = tid & 63;
  const int wm = wave >> 2;  // 0..1  M half (128 rows)
  const int wn = wave & 3;   // 0..3  N quarter (64 cols)

  const int nwg = gridDim.x;
  const int bid = blockIdx.x;
  const int swz =
      ((nwg & 7) == 0) ? ((bid & 7) * (nwg >> 3) + (bid >> 3)) : bid;
  const int ntn = N / BN;
  const int by = swz / ntn, bx = swz % ntn;
  const int bm0 = by * BM, bn0 = bx * BN;

  const int ldr = lane >> 3;
  const int ldc = ((lane & 7) ^ ldr) * 8;
  const ushort* Ag = A + (size_t)(bm0 + wave * 16 + ldr) * K + ldc;
  const ushort* Bg = B + (size_t)(bn0 + wave * 16 + ldr) * K + ldc;

#define STAGE_A(b, h, kt)                                          \
  do {                                                             \
    glds16(Ag + (size_t)((h) * 128) * K + (size_t)(kt) * BK,       \
           &As[b][((h) * 128 + wave * 16) * BK]);                  \
    glds16(Ag + (size_t)((h) * 128 + 8) * K + (size_t)(kt) * BK,   \
           &As[b][((h) * 128 + wave * 16 + 8) * BK]);              \
  } while (0)
#define STAGE_B(b, h, kt)                                          \
  do {                                                             \
    glds16(Bg + (size_t)((h) * 128) * K + (size_t)(kt) * BK,       \
           &Bs[b][((h) * 128 + wave * 16) * BK]);                  \
    glds16(Bg + (size_t)((h) * 128 + 8) * K + (size_t)(kt) * BK,   \
           &Bs[b][((h) * 128 + wave * 16 + 8) * BK]);              \
  } while (0)

  const int mrow = lane & 15;
  const int kc = lane >> 4;
  const int sw = mrow & 7;
  const int c0 = (kc ^ sw) * 8;
  const int c1 = ((4 + kc) ^ sw) * 8;
  const int aBase = (wm * 128 + mrow) * BK;
  const int bBase = (wn * 64 + mrow) * BK;

  f32x4 acc[8][4];
#pragma unroll
  for (int i = 0; i < 8; ++i)
#pragma unroll
    for (int j = 0; j < 4; ++j) acc[i][j] = (f32x4){0.f, 0.f, 0.f, 0.f};

  const int NT = K / BK;

  STAGE_A(0, 0, 0);
  STAGE_A(0, 1, 0);
  STAGE_B(0, 0, 0);
  STAGE_B(0, 1, 0);
  STAGE_B(1, 0, 1);
  STAGE_B(1, 1, 1);
  __builtin_amdgcn_sched_barrier(0);
  asm volatile("s_waitcnt vmcnt(4)" ::: "memory");
  __builtin_amdgcn_s_barrier();

  bf16x8 a[4][2], b[4][2];

  for (int kt = 0; kt < NT; ++kt) {
    const int cur = kt & 1, nxt = cur ^ 1;
    const ushort* Ac = As[cur];
    const ushort* Bc = Bs[cur];

    // ================= phase 1: (m0-3) x (n0-1) =================
#pragma unroll
    for (int mi = 0; mi < 4; ++mi) {
      a[mi][0] = *(const bf16x8*)&Ac[aBase + mi * (16 * BK) + c0];
      a[mi][1] = *(const bf16x8*)&Ac[aBase + mi * (16 * BK) + c1];
    }
#pragma unroll
    for (int ni = 0; ni < 2; ++ni) {
      b[ni][0] = *(const bf16x8*)&Bc[bBase + ni * (16 * BK) + c0];
      b[ni][1] = *(const bf16x8*)&Bc[bBase + ni * (16 * BK) + c1];
    }
    if (kt + 1 < NT) STAGE_A(nxt, 0, kt + 1);
    __builtin_amdgcn_sched_barrier(0);
    __builtin_amdgcn_s_barrier();
    __builtin_amdgcn_s_setprio(1);
#pragma unroll
    for (int ks = 0; ks < 2; ++ks)
#pragma unroll
      for (int mi = 0; mi < 4; ++mi)
#pragma unroll
        for (int ni = 0; ni < 2; ++ni)
          acc[mi][ni] = __builtin_amdgcn_mfma_f32_16x16x32_bf16(
              a[mi][ks], b[ni][ks], acc[mi][ni], 0, 0, 0);
    __builtin_amdgcn_s_setprio(0);
    __builtin_amdgcn_sched_barrier(0);
    __builtin_amdgcn_s_barrier();

    // ================= phase 2: (m0-3) x (n2-3) =================
#pragma unroll
    for (int ni = 2; ni < 4; ++ni) {
      b[ni][0] = *(const bf16x8*)&Bc[bBase + ni * (16 * BK) + c0];
      b[ni][1] = *(const bf16x8*)&Bc[bBase + ni * (16 * BK) + c1];
    }
    if (kt + 1 < NT) STAGE_A(nxt, 1, kt + 1);
    __builtin_amdgcn_sched_barrier(0);
    __builtin_amdgcn_s_barrier();
    __builtin_amdgcn_s_setprio(1);
#pragma unroll
    for (int ks = 0; ks < 2; ++ks)
#pragma unroll
      for (int mi = 0; mi < 4; ++mi)
#pragma unroll
        for (int ni = 2; ni < 4; ++ni)
          acc[mi][ni] = __builtin_amdgcn_mfma_f32_16x16x32_bf16(
              a[mi][ks], b[ni][ks], acc[mi][ni], 0, 0, 0);
    __builtin_amdgcn_s_setprio(0);
    __builtin_amdgcn_sched_barrier(0);
    __builtin_amdgcn_s_barrier();

    // ================= phase 3: (m4-7) x (n2-3) =================
#pragma unroll
    for (int mi = 0; mi < 4; ++mi) {
      a[mi][0] = *(const bf16x8*)&Ac[aBase + (mi + 4) * (16 * BK) + c0];
      a[mi][1] = *(const bf16x8*)&Ac[aBase + (mi + 4) * (16 * BK) + c1];
    }
    if (kt + 2 < NT) STAGE_B(cur, 0, kt + 2);
    __builtin_amdgcn_sched_barrier(0);
    __builtin_amdgcn_s_barrier();
    __builtin_amdgcn_s_setprio(1);
#pragma unroll
    for (int ks = 0; ks < 2; ++ks)
#pragma unroll
      for (int mi = 0; mi < 4; ++mi)
#pragma unroll
        for (int ni = 2; ni < 4; ++ni)
          acc[mi + 4][ni] = __builtin_amdgcn_mfma_f32_16x16x32_bf16(
              a[mi][ks], b[ni][ks], acc[mi + 4][ni], 0, 0, 0);
    __builtin_amdgcn_s_setprio(0);
    __builtin_amdgcn_sched_barrier(0);
    __builtin_amdgcn_s_barrier();

    // ================= phase 4: (m4-7) x (n0-1) =================
    if (kt + 2 < NT) STAGE_B(cur, 1, kt + 2);
    __builtin_amdgcn_sched_barrier(0);
    if (kt < NT - 2)
      asm volatile("s_waitcnt vmcnt(4)" ::: "memory");
    else
      asm volatile("s_waitcnt vmcnt(0)" ::: "memory");
    __builtin_amdgcn_s_barrier();
    __builtin_amdgcn_s_setprio(1);
#pragma unroll
    for (int ks = 0; ks < 2; ++ks)
#pragma unroll
      for (int mi = 0; mi < 4; ++mi)
#pragma unroll
        for (int ni = 0; ni < 2; ++ni)
          acc[mi + 4][ni] = __builtin_amdgcn_mfma_f32_16x16x32_bf16(
              a[mi][ks], b[ni][ks], acc[mi + 4][ni], 0, 0, 0);
    __builtin_amdgcn_s_setprio(0);
    __builtin_amdgcn_sched_barrier(0);
    __builtin_amdgcn_s_barrier();
  }

  const int col = lane & 15;
  const int rq = (lane >> 4) * 4;
#pragma unroll
  for (int mi = 0; mi < 8; ++mi)
#pragma unroll
    for (int ni = 0; ni < 4; ++ni) {
      const int r0 = bm0 + wm * 128 + mi * 16 + rq;
      const int c = bn0 + wn * 64 + ni * 16 + col;
#pragma unroll
      for (int r = 0; r < 4; ++r)
        C[(size_t)(r0 + r) * N + c] = acc[mi][ni][r];
    }
#undef STAGE_A
#undef STAGE_B
}

extern "C" void kernel_launch(void* const* d_in, const int* in_sizes, int n_in,
                              void* d_out, int out_size, void* d_ws,
                              size_t ws_size, hipStream_t stream) {
  const float* x = (const float*)d_in[0];
  const int* w = (const int*)d_in[1];
  const float* scales = (const float*)d_in[2];
  const float* zeros = (const float*)d_in[3];
  float* out = (float*)d_out;

  const double ii =
      sqrt((double)in_sizes[0] * (double)in_sizes[1] / (double)out_size);
  const int I = (int)(ii + 0.5);
  const int T = in_sizes[0] / I;
  const int O = in_sizes[1] / I;
  const int G = I / 256;

  ushort* xq = (ushort*)d_ws;       // T*I bf16
  ushort* wq = xq + (size_t)T * I;  // O*I bf16

  const int XB = T / 4;                          // x blocks (4 rows each)
  const int WB = (int)(((long long)O * I) >> 13);  // w blocks (2048 chunks)
  prep_fused<<<XB + WB, 256, 0, stream>>>(x, xq, T, w, scales, zeros, wq, I, G);
  gemm_bt256<<<(O / BN) * (T / BM), 512, 0, stream>>>(xq, wq, out, T, O, I);
}

// Round 3
// 506.903 us; speedup vs baseline: 1.1678x; 1.0216x over previous
//
#include <hip/hip_runtime.h>
#include <hip/hip_bf16.h>
#include <math.h>

typedef __attribute__((ext_vector_type(8))) __bf16 bf16x8;
typedef __attribute__((ext_vector_type(4))) float f32x4;

#define BM 256
#define BN 256
#define BK 64

__device__ __forceinline__ void glds16(const void* g, void* l) {
  __builtin_amdgcn_global_load_lds(
      (const __attribute__((address_space(1))) void*)g,
      (__attribute__((address_space(3))) void*)l, 16, 0, 0);
}

__device__ __forceinline__ unsigned short f2bf(float f) {
  __hip_bfloat16 h = __float2bfloat16(f);
  return __builtin_bit_cast(unsigned short, h);
}

// ---------------- prep_x: per-token int8 fake-quant -> bf16 ----------------
// One token row PER WAVE: lane holds the row slice in registers (16 x
// float4, all loads in flight), butterfly shfl_xor allreduce, every lane
// computes qparams redundantly, quantizes from registers. 4 rows/block.
__global__ __launch_bounds__(256) void prep_x(const float* __restrict__ x,
                                              ushort* __restrict__ xq,
                                              int I) {
  const int wave = threadIdx.x >> 6, lane = threadIdx.x & 63;
  const int row = blockIdx.x * 4 + wave;
  const float4* xr = (const float4*)(x + (size_t)row * I);
  float4 v[16];  // I/4 float4 per row / 64 lanes = 16 (I = 4096)
#pragma unroll
  for (int j = 0; j < 16; ++j) v[j] = xr[lane + j * 64];
  float mn = 0.f, mx = 0.f;  // reference clamps min<=0, max>=0
#pragma unroll
  for (int j = 0; j < 16; ++j) {
    mn = fminf(mn, fminf(fminf(v[j].x, v[j].y), fminf(v[j].z, v[j].w)));
    mx = fmaxf(mx, fmaxf(fmaxf(v[j].x, v[j].y), fmaxf(v[j].z, v[j].w)));
  }
#pragma unroll
  for (int off = 32; off > 0; off >>= 1) {
    mn = fminf(mn, __shfl_xor(mn, off));
    mx = fmaxf(mx, __shfl_xor(mx, off));
  }
  const float scale = fmaxf((mx - mn) / 255.0f, 1.1920928955078125e-07f);
  const float dmin = mn / scale, dmax = mx / scale;
  float zp = ((-128.0f + dmin) + (127.0f + dmax) > 0.0f) ? (-128.0f - dmin)
                                                         : (127.0f - dmax);
  zp = rintf(fminf(fmaxf(zp, -128.0f), 127.0f));  // jnp.round = RNE
  const float rs = 1.0f / scale;
  ushort4* xo = (ushort4*)(xq + (size_t)row * I);
#pragma unroll
  for (int j = 0; j < 16; ++j) {
    ushort4 o;
    float q;
    q = fminf(fmaxf(rintf(v[j].x * rs) + zp, -128.f), 127.f);
    o.x = f2bf((q - zp) * scale);
    q = fminf(fmaxf(rintf(v[j].y * rs) + zp, -128.f), 127.f);
    o.y = f2bf((q - zp) * scale);
    q = fminf(fmaxf(rintf(v[j].z * rs) + zp, -128.f), 127.f);
    o.z = f2bf((q - zp) * scale);
    q = fminf(fmaxf(rintf(v[j].w * rs) + zp, -128.f), 127.f);
    o.w = f2bf((q - zp) * scale);
    xo[lane + j * 64] = o;
  }
}

// ---------------- prep_w: groupwise int4 weight dequant -> bf16 ------------
// Flat streaming: each block owns 2048 contiguous int4-chunks; 8 unrolled
// independent 16B loads/thread. A wave's 64 consecutive chunks = one
// 256-elem group -> group id wave-uniform; readfirstlane -> scalar loads.
__global__ __launch_bounds__(256) void prep_w(const int* __restrict__ w,
                                              const float* __restrict__ scales,
                                              const float* __restrict__ zeros,
                                              ushort* __restrict__ wq) {
  const long long base = (long long)blockIdx.x * 2048 + threadIdx.x;
  const int4* wr = (const int4*)w;
  ushort4* wo = (ushort4*)wq;
  int4 wv[8];
#pragma unroll
  for (int it = 0; it < 8; ++it) wv[it] = wr[base + (size_t)it * 256];
#pragma unroll
  for (int it = 0; it < 8; ++it) {
    const long long c = base + (size_t)it * 256;
    const int g = __builtin_amdgcn_readfirstlane((int)(c >> 6));
    const float s = scales[g];
    const float z = zeros[g];
    ushort4 ov;
    ov.x = f2bf(((float)wv[it].x - z) * s);
    ov.y = f2bf(((float)wv[it].y - z) * s);
    ov.z = f2bf(((float)wv[it].z - z) * s);
    ov.w = f2bf(((float)wv[it].w - z) * s);
    wo[c] = ov;
  }
}

// ---------------- bf16 NT GEMM: 256x256 tile, BK=64, 8 waves, 8-phase ------
// C[M,N] = A[M,K] * B[N,K]^T.
// R3 changes vs R2 (codegen only; runtime barrier/vmcnt schedule identical):
//  - 2 K-tiles per iteration with compile-time buffer parity (CUR macro
//    param) -> static LDS addresses, no runtime cur/nxt arithmetic.
//  - last two K-tiles peeled -> no per-phase guards in the steady loop.
//  - sched_barrier(0) pins removed except directly after each inline vmcnt
//    (m141: order-pinning defeats the compiler scheduler; rule #18 only
//    requires the pin after inline-asm lgkm waits, which we don't use).
__global__ __launch_bounds__(512, 2) void gemm_bt256(
    const ushort* __restrict__ A, const ushort* __restrict__ B,
    float* __restrict__ C, int M, int N, int K) {
  __shared__ __align__(16) ushort As[2][BM * BK];
  __shared__ __align__(16) ushort Bs[2][BN * BK];
  const int tid = threadIdx.x;
  const int wave = tid >> 6, lane = tid & 63;
  const int wm = wave >> 2;  // 0..1  M half (128 rows)
  const int wn = wave & 3;   // 0..3  N quarter (64 cols)

  // XCD-aware bijective swizzle (nwg % 8 == 0 here: 512 blocks)
  const int nwg = gridDim.x;
  const int bid = blockIdx.x;
  const int swz =
      ((nwg & 7) == 0) ? ((bid & 7) * (nwg >> 3) + (bid >> 3)) : bid;
  const int ntn = N / BN;
  const int by = swz / ntn, bx = swz % ntn;
  const int bm0 = by * BM, bn0 = bx * BN;

  // staging: global source pre-swizzled so physical 16B chunk c of LDS row
  // r holds logical k-chunk c ^ (r&7); glds writes base + lane*16 linearly.
  const int ldr = lane >> 3;
  const int ldc = ((lane & 7) ^ ldr) * 8;
  const ushort* Ag = A + (size_t)(bm0 + wave * 16 + ldr) * K + ldc;
  const ushort* Bg = B + (size_t)(bn0 + wave * 16 + ldr) * K + ldc;

#define STAGE_A(b, h, kt)                                        \
  do {                                                           \
    glds16(Ag + (size_t)((h) * 128) * K + (size_t)(kt) * BK,     \
           &As[b][((h) * 128 + wave * 16) * BK]);                \
    glds16(Ag + (size_t)((h) * 128 + 8) * K + (size_t)(kt) * BK, \
           &As[b][((h) * 128 + wave * 16 + 8) * BK]);            \
  } while (0)
#define STAGE_B(b, h, kt)                                        \
  do {                                                           \
    glds16(Bg + (size_t)((h) * 128) * K + (size_t)(kt) * BK,     \
           &Bs[b][((h) * 128 + wave * 16) * BK]);                \
    glds16(Bg + (size_t)((h) * 128 + 8) * K + (size_t)(kt) * BK, \
           &Bs[b][((h) * 128 + wave * 16 + 8) * BK]);            \
  } while (0)

  // fragment reads: physical chunk = logical ^ (row&7)
  const int mrow = lane & 15;
  const int kc = lane >> 4;
  const int sw = mrow & 7;
  const int c0 = (kc ^ sw) * 8;
  const int c1 = ((4 + kc) ^ sw) * 8;
  const int aBase = (wm * 128 + mrow) * BK;
  const int bBase = (wn * 64 + mrow) * BK;

  f32x4 acc[8][4];
#pragma unroll
  for (int i = 0; i < 8; ++i)
#pragma unroll
    for (int j = 0; j < 4; ++j) acc[i][j] = (f32x4){0.f, 0.f, 0.f, 0.f};

  const int NT = K / BK;  // 64 for K=4096 (assumed even, >= 4)

  // prologue: kt0 fully + B(kt1); leave B(kt1) (4 loads) in flight
  STAGE_A(0, 0, 0);
  STAGE_A(0, 1, 0);
  STAGE_B(0, 0, 0);
  STAGE_B(0, 1, 0);
  STAGE_B(1, 0, 1);
  STAGE_B(1, 1, 1);
  asm volatile("s_waitcnt vmcnt(4)" ::: "memory");
  __builtin_amdgcn_sched_barrier(0);
  __builtin_amdgcn_s_barrier();

  bf16x8 a[4][2], b[4][2];

#define MFMA8(MI0, NI0)                                                    \
  __builtin_amdgcn_s_setprio(1);                                           \
  _Pragma("unroll") for (int ks = 0; ks < 2; ++ks)                         \
      _Pragma("unroll") for (int mi = 0; mi < 4; ++mi)                     \
          _Pragma("unroll") for (int ni = 0; ni < 2; ++ni) acc[(MI0) + mi] \
              [(NI0) + ni] = __builtin_amdgcn_mfma_f32_16x16x32_bf16(      \
                  a[mi][ks], b[(NI0) + ni][ks], acc[(MI0) + mi][(NI0) + ni], \
                  0, 0, 0);                                                \
  __builtin_amdgcn_s_setprio(0);

// One K-tile = 4 phases. CUR is compile-time (0/1). DO_SA stages A(kt+1)
// into buffer 1-CUR; DO_SB stages B(kt+2) into buffer CUR (its reads end
// at phase 2). WAITN: 1 -> vmcnt(4) steady state, 0 -> vmcnt(0) drain.
#define KTILE(CUR, KT, DO_SA, DO_SB, WAIT4)                          \
  do {                                                               \
    const ushort* Ac = As[CUR];                                      \
    const ushort* Bc = Bs[CUR];                                      \
    /* ---- phase 1: (m0-3) x (n0-1) ---- */                         \
    _Pragma("unroll") for (int mi = 0; mi < 4; ++mi) {               \
      a[mi][0] = *(const bf16x8*)&Ac[aBase + mi * (16 * BK) + c0];   \
      a[mi][1] = *(const bf16x8*)&Ac[aBase + mi * (16 * BK) + c1];   \
    }                                                                \
    _Pragma("unroll") for (int ni = 0; ni < 2; ++ni) {               \
      b[ni][0] = *(const bf16x8*)&Bc[bBase + ni * (16 * BK) + c0];   \
      b[ni][1] = *(const bf16x8*)&Bc[bBase + ni * (16 * BK) + c1];   \
    }                                                                \
    if (DO_SA) STAGE_A(1 - (CUR), 0, (KT) + 1);                      \
    __builtin_amdgcn_s_barrier();                                    \
    MFMA8(0, 0)                                                      \
    __builtin_amdgcn_s_barrier();                                    \
    /* ---- phase 2: (m0-3) x (n2-3) ---- */                         \
    _Pragma("unroll") for (int ni = 2; ni < 4; ++ni) {               \
      b[ni][0] = *(const bf16x8*)&Bc[bBase + ni * (16 * BK) + c0];   \
      b[ni][1] = *(const bf16x8*)&Bc[bBase + ni * (16 * BK) + c1];   \
    }                                                                \
    if (DO_SA) STAGE_A(1 - (CUR), 1, (KT) + 1);                      \
    __builtin_amdgcn_s_barrier();                                    \
    MFMA8(0, 2)                                                      \
    __builtin_amdgcn_s_barrier();                                    \
    /* ---- phase 3: (m4-7) x (n2-3) ---- */                         \
    _Pragma("unroll") for (int mi = 0; mi < 4; ++mi) {               \
      a[mi][0] =                                                     \
          *(const bf16x8*)&Ac[aBase + (mi + 4) * (16 * BK) + c0];    \
      a[mi][1] =                                                     \
          *(const bf16x8*)&Ac[aBase + (mi + 4) * (16 * BK) + c1];    \
    }                                                                \
    if (DO_SB) STAGE_B(CUR, 0, (KT) + 2);                            \
    __builtin_amdgcn_s_barrier();                                    \
    MFMA8(4, 2)                                                      \
    __builtin_amdgcn_s_barrier();                                    \
    /* ---- phase 4: (m4-7) x (n0-1) ---- */                         \
    if (DO_SB) STAGE_B(CUR, 1, (KT) + 2);                            \
    if (WAIT4)                                                       \
      asm volatile("s_waitcnt vmcnt(4)" ::: "memory");               \
    else                                                             \
      asm volatile("s_waitcnt vmcnt(0)" ::: "memory");               \
    __builtin_amdgcn_sched_barrier(0);                               \
    __builtin_amdgcn_s_barrier();                                    \
    MFMA8(4, 0)                                                      \
    __builtin_amdgcn_s_barrier();                                    \
  } while (0)

  int kt = 0;
  for (; kt < NT - 2; kt += 2) {
    KTILE(0, kt, 1, 1, 1);
    KTILE(1, kt + 1, 1, 1, 1);
  }
  // peeled tail: tile NT-2 stages A(NT-1) only and fully drains; NT-1 clean
  KTILE(0, kt, 1, 0, 0);
  KTILE(1, kt + 1, 0, 0, 0);

  // epilogue: C/D layout col=lane&15, row=(lane>>4)*4+reg
  const int col = lane & 15;
  const int rq = (lane >> 4) * 4;
#pragma unroll
  for (int mi = 0; mi < 8; ++mi)
#pragma unroll
    for (int ni = 0; ni < 4; ++ni) {
      const int r0 = bm0 + wm * 128 + mi * 16 + rq;
      const int c = bn0 + wn * 64 + ni * 16 + col;
#pragma unroll
      for (int r = 0; r < 4; ++r)
        C[(size_t)(r0 + r) * N + c] = acc[mi][ni][r];
    }
#undef KTILE
#undef MFMA8
#undef STAGE_A
#undef STAGE_B
}

extern "C" void kernel_launch(void* const* d_in, const int* in_sizes, int n_in,
                              void* d_out, int out_size, void* d_ws,
                              size_t ws_size, hipStream_t stream) {
  const float* x = (const float*)d_in[0];
  const int* w = (const int*)d_in[1];
  const float* scales = (const float*)d_in[2];
  const float* zeros = (const float*)d_in[3];
  float* out = (float*)d_out;

  const double ii =
      sqrt((double)in_sizes[0] * (double)in_sizes[1] / (double)out_size);
  const int I = (int)(ii + 0.5);
  const int T = in_sizes[0] / I;
  const int O = in_sizes[1] / I;

  ushort* xq = (ushort*)d_ws;       // T*I bf16
  ushort* wq = xq + (size_t)T * I;  // O*I bf16

  prep_x<<<T / 4, 256, 0, stream>>>(x, xq, I);
  prep_w<<<(int)(((long long)O * I) >> 13), 256, 0, stream>>>(w, scales,
                                                              zeros, wq);
  gemm_bt256<<<(O / BN) * (T / BM), 512, 0, stream>>>(xq, wq, out, T, O, I);
}